// Round 4
// baseline (307.662 us; speedup 1.0000x reference)
//
#include <hip/hip_runtime.h>
#include <hip/hip_bf16.h>

typedef __attribute__((ext_vector_type(4))) float f32x4;
typedef __attribute__((ext_vector_type(4))) short s16x4;
typedef __attribute__((ext_vector_type(8))) short s16x8;
typedef __attribute__((ext_vector_type(8))) __bf16 bf16x8;

#define DEV static __device__ __forceinline__

DEV float bf2f(ushort u){
  unsigned x = ((unsigned)u) << 16;
  return __builtin_bit_cast(float, x);
}
DEV ushort f2bf(float f){
  unsigned x = __builtin_bit_cast(unsigned, f);
  x += 0x7fffu + ((x >> 16) & 1u);
  return (ushort)(x >> 16);
}
DEV void load_lds16(const void* g, void* l){
  __builtin_amdgcn_global_load_lds((const __attribute__((address_space(1))) void*)g,
                                   (__attribute__((address_space(3))) void*)l, 16, 0, 0);
}

// ---------------- stage 0a: x fp32 -> bf16 ----------------
__global__ __launch_bounds__(256) void k_cvt_x(const float* __restrict__ x,
                                               ushort* __restrict__ xb, int n8){
  int i = blockIdx.x * 256 + threadIdx.x;
  if (i >= n8) return;
  const f32x4* p = (const f32x4*)(x + (size_t)i * 8);
  f32x4 a = p[0], b = p[1];
  s16x8 o;
  o[0]=(short)f2bf(a[0]); o[1]=(short)f2bf(a[1]); o[2]=(short)f2bf(a[2]); o[3]=(short)f2bf(a[3]);
  o[4]=(short)f2bf(b[0]); o[5]=(short)f2bf(b[1]); o[6]=(short)f2bf(b[2]); o[7]=(short)f2bf(b[3]);
  *(s16x8*)(xb + (size_t)i * 8) = o;
}

// ---------------- stage 0b: W [K][N] fp32 -> Wt [N][K] bf16 ----------------
__global__ void k_transposeW(const float* __restrict__ Wq, const float* __restrict__ Wk,
                             const float* __restrict__ Wv, const float* __restrict__ Wp,
                             ushort* __restrict__ qkvT, ushort* __restrict__ wpT){
  __shared__ float tile[32][33];
  int z = blockIdx.z;
  const float* W = (z == 0) ? Wq : (z == 1) ? Wk : (z == 2) ? Wv : Wp;
  ushort* out = (z < 3) ? (qkvT + (size_t)z * 1024 * 1024) : wpT;
  int bx = blockIdx.x * 32, by = blockIdx.y * 32;
  int tx = threadIdx.x, ty = threadIdx.y;
  #pragma unroll
  for (int j = 0; j < 32; j += 8)
    tile[ty + j][tx] = W[(size_t)(by + ty + j) * 1024 + bx + tx];
  __syncthreads();
  #pragma unroll
  for (int j = 0; j < 32; j += 8)
    out[(size_t)(bx + ty + j) * 1024 + by + tx] = f2bf(tile[tx][ty + j]);
}

// ---------------- MFMA GEMM, 256x256 tile, BK=64, 4-phase, burst prefetch --
// C[M][N] = A[M][K] * Bt[N][K]^T, K=1024. 512 threads = 8 waves (2Mx4N),
// per-wave 128x64. Phases per K-tile: (mh0,kk0),(mh1,kk0),(mh1,kk1),(mh0,kk1).
// ALL 8 staging rounds for tile t+1 are issued in a burst at ph1 of tile t
// (order: B0,B1,B2,B3,A0,A2, then A1,A3 last). Waits:
//   end-ph1 vmcnt(8): current tile's A1,A3 landed (issued 4 phases earlier)
//   end-ph4 vmcnt(2): t+1's B+A0+A2 landed (3-phase lead), A1,A3 in flight.
// Both leads >= HBM latency -> waits are cheap. Race-safety: buf^1 is dead
// for all of tile t (t-1's reads drained by per-phase lgkmcnt(0)+barrier).
// LDS swizzle: 16B-granule ^= row&7 (A) / (row>>2)&7 (B); frag reads at
// granule hi^(L&7): 2-way, free. B-frag N-permutation: slot L holds B-row
// wc*64+L*4+n -> lane's 4 n-accumulators are 4 contiguous output cols.
template<int MODE>
__global__ __launch_bounds__(512, 2) void k_gemm(
    const ushort* __restrict__ A, const ushort* __restrict__ Bt,
    const float* __restrict__ b0, const float* __restrict__ b1, const float* __restrict__ b2,
    ushort* __restrict__ oQ, ushort* __restrict__ oK, ushort* __restrict__ oV,
    float* __restrict__ oF, int N)
{
  const int K = 1024;
  const int NT = 16;                        // K / 64
  __shared__ ushort ldsA[2][16384];         // 2 x 32KB: [256 rows][64 cols bf16]
  __shared__ ushort ldsB[2][16384];

  int wg = blockIdx.x;
  int cpx = gridDim.x >> 3;                 // grids are multiples of 8
  wg = (wg & 7) * cpx + (wg >> 3);          // XCD-aware swizzle (bijective)
  int nbn = N >> 8;
  int bmi = wg / nbn, bni = wg - bmi * nbn;
  int m0 = bmi << 8, n0 = bni << 8;
  int tid = threadIdx.x, wid = tid >> 6, lane = tid & 63;
  int wr = wid >> 2, wc = wid & 3;
  int hi = lane >> 4, L = lane & 15;

  // ---- staging sources (linear LDS dest, inverse-swizzled global source)
  int rr = tid >> 3;                                   // row within 8KB round
  int gaA = ((tid & 7) ^ (rr & 7)) << 3;               // A src col (elements)
  int gaB = ((tid & 7) ^ ((tid >> 5) & 7)) << 3;       // B src col (elements)
  const ushort* gA = A  + (size_t)(m0 + rr) * K + gaA; // + rowbase*K + k
  const ushort* gB = Bt + (size_t)(n0 + rr) * K + gaB;
  int ldst = wid << 10;                                // + round*8192 (+buf*32768)

  // ---- fragment read addresses
  int swz = (hi ^ (L & 7)) << 4;            // ^ 64 for kk=1
  int arow = (wr * 128 + L) << 7;           // + mh*8192 + m*2048
  int brow = ((wc * 64 + L * 4)) << 7;      // + n*128

  f32x4 acc[8][4] = {};
  bf16x8 af[4], bf[4];

  // burst-stage one full tile (8 rounds; A1,A3 issued LAST)
  #define STAGE_TILE(SA, SB, kof)                                   \
    load_lds16(gB + (kof),                   (SB) + ldst);          \
    load_lds16(gB + (size_t) 64 * K + (kof), (SB) + 8192  + ldst);  \
    load_lds16(gB + (size_t)128 * K + (kof), (SB) + 16384 + ldst);  \
    load_lds16(gB + (size_t)192 * K + (kof), (SB) + 24576 + ldst);  \
    load_lds16(gA + (kof),                   (SA) + ldst);          \
    load_lds16(gA + (size_t)128 * K + (kof), (SA) + 16384 + ldst);  \
    load_lds16(gA + (size_t) 64 * K + (kof), (SA) + 8192  + ldst);  \
    load_lds16(gA + (size_t)192 * K + (kof), (SA) + 24576 + ldst);

  // ---- prologue: stage tile 0 into buf 0
  STAGE_TILE((char*)&ldsA[0][0], (char*)&ldsB[0][0], 0)
  asm volatile("s_waitcnt vmcnt(2)" ::: "memory");  // B0-3 + A0,A2 landed
  __builtin_amdgcn_s_barrier();

  int buf = 0;
  for (int t = 0; t < NT; ++t) {
    const char* LA = (const char*)&ldsA[buf][0];
    const char* LB = (const char*)&ldsB[buf][0];
    char* SA = (char*)&ldsA[buf ^ 1][0];
    char* SB = (char*)&ldsB[buf ^ 1][0];
    size_t k1 = (size_t)(t + 1) << 6;
    bool st = (t + 1) < NT;

    // ======== phase 1: (mh=0, kk=0) ======== [burst-stage tile t+1]
    #pragma unroll
    for (int m = 0; m < 4; ++m) af[m] = *(const bf16x8*)(LA + arow + (m << 11) + swz);
    #pragma unroll
    for (int n = 0; n < 4; ++n) bf[n] = *(const bf16x8*)(LB + brow + (n << 7) + swz);
    if (st) { STAGE_TILE(SA, SB, k1) }
    __builtin_amdgcn_s_barrier();
    asm volatile("s_waitcnt lgkmcnt(0)" ::: "memory");
    __builtin_amdgcn_s_setprio(1);
    #pragma unroll
    for (int m = 0; m < 4; ++m)
      #pragma unroll
      for (int n = 0; n < 4; ++n)
        acc[m][n] = __builtin_amdgcn_mfma_f32_16x16x32_bf16(af[m], bf[n], acc[m][n], 0, 0, 0);
    __builtin_amdgcn_s_setprio(0);
    if (st) asm volatile("s_waitcnt vmcnt(8)" ::: "memory");  // t's A1,A3 landed
    else    asm volatile("s_waitcnt vmcnt(0)" ::: "memory");
    __builtin_amdgcn_s_barrier();

    // ======== phase 2: (mh=1, kk=0) ========
    #pragma unroll
    for (int m = 0; m < 4; ++m) af[m] = *(const bf16x8*)(LA + arow + 8192 + (m << 11) + swz);
    __builtin_amdgcn_s_barrier();
    asm volatile("s_waitcnt lgkmcnt(0)" ::: "memory");
    __builtin_amdgcn_s_setprio(1);
    #pragma unroll
    for (int m = 0; m < 4; ++m)
      #pragma unroll
      for (int n = 0; n < 4; ++n)
        acc[m + 4][n] = __builtin_amdgcn_mfma_f32_16x16x32_bf16(af[m], bf[n], acc[m + 4][n], 0, 0, 0);
    __builtin_amdgcn_s_setprio(0);
    __builtin_amdgcn_s_barrier();

    // ======== phase 3: (mh=1, kk=1) ========
    #pragma unroll
    for (int m = 0; m < 4; ++m) af[m] = *(const bf16x8*)(LA + arow + 8192 + (m << 11) + (swz ^ 64));
    #pragma unroll
    for (int n = 0; n < 4; ++n) bf[n] = *(const bf16x8*)(LB + brow + (n << 7) + (swz ^ 64));
    __builtin_amdgcn_s_barrier();
    asm volatile("s_waitcnt lgkmcnt(0)" ::: "memory");
    __builtin_amdgcn_s_setprio(1);
    #pragma unroll
    for (int m = 0; m < 4; ++m)
      #pragma unroll
      for (int n = 0; n < 4; ++n)
        acc[m + 4][n] = __builtin_amdgcn_mfma_f32_16x16x32_bf16(af[m], bf[n], acc[m + 4][n], 0, 0, 0);
    __builtin_amdgcn_s_setprio(0);
    __builtin_amdgcn_s_barrier();

    // ======== phase 4: (mh=0, kk=1) ========
    #pragma unroll
    for (int m = 0; m < 4; ++m) af[m] = *(const bf16x8*)(LA + arow + (m << 11) + (swz ^ 64));
    __builtin_amdgcn_s_barrier();
    asm volatile("s_waitcnt lgkmcnt(0)" ::: "memory");
    __builtin_amdgcn_s_setprio(1);
    #pragma unroll
    for (int m = 0; m < 4; ++m)
      #pragma unroll
      for (int n = 0; n < 4; ++n)
        acc[m][n] = __builtin_amdgcn_mfma_f32_16x16x32_bf16(af[m], bf[n], acc[m][n], 0, 0, 0);
    __builtin_amdgcn_s_setprio(0);
    if (st) asm volatile("s_waitcnt vmcnt(2)" ::: "memory");  // t+1's B,A0,A2 landed
    __builtin_amdgcn_s_barrier();
    buf ^= 1;
  }
  #undef STAGE_TILE

  // ---- epilogue: lane holds 4 contiguous cols (cb4..cb4+3) per row
  int row0 = m0 + wr * 128 + (hi << 2);
  int cb4 = n0 + wc * 64 + (L << 2);
  if constexpr (MODE == 0) {
    f32x4 bias; ushort* dst; bool act;
    if (cb4 < 1024)      { bias = *(const f32x4*)(b0 + cb4);          dst = oQ + cb4;          act = true;  }
    else if (cb4 < 2048) { bias = *(const f32x4*)(b1 + (cb4 - 1024)); dst = oK + (cb4 - 1024); act = true;  }
    else                 { bias = *(const f32x4*)(b2 + (cb4 - 2048)); dst = oV + (cb4 - 2048); act = false; }
    #pragma unroll
    for (int m = 0; m < 8; ++m)
      #pragma unroll
      for (int j = 0; j < 4; ++j) {
        int r = row0 + m * 16 + j;
        s16x4 w;
        #pragma unroll
        for (int n = 0; n < 4; ++n) {
          float v = acc[m][n][j] + bias[n];
          if (act) v = (v > 0.f) ? (v + 1.f) : __expf(v);   // elu(v)+1
          w[n] = (short)f2bf(v);
        }
        *(s16x4*)(dst + (size_t)r * 1024) = w;
      }
  } else {
    f32x4 bias = *(const f32x4*)(b0 + cb4);
    #pragma unroll
    for (int m = 0; m < 8; ++m)
      #pragma unroll
      for (int j = 0; j < 4; ++j) {
        int r = row0 + m * 16 + j;
        f32x4 w;
        #pragma unroll
        for (int n = 0; n < 4; ++n) w[n] = acc[m][n][j] + bias[n];
        *(f32x4*)(oF + (size_t)r * 1024 + cb4) = w;
      }
  }
}

// ---------------- stage 2: kv[bh][64][64] = k^T v ; sumk[bh][64] ----------------
__global__ __launch_bounds__(256, 2) void k_kv(
    const ushort* __restrict__ kbuf, const ushort* __restrict__ vbuf,
    float* __restrict__ kvg, float* __restrict__ sumkg)
{
  __shared__ ushort lds[8192];               // Ks 8KB | Vs 8KB ; reused as fp32 red
  int bh = blockIdx.x >> 3, chunk = blockIdx.x & 7;
  int b = bh >> 4, h = bh & 15;
  int tid = threadIdx.x, wid = tid >> 6, lane = tid & 63;
  int d0 = (lane >> 3) << 3, e0 = (lane & 7) << 3;
  float acc[8][8] = {};
  float sk[8] = {};
  size_t rowbase = ((size_t)b * 4096 + chunk * 512) * 1024 + h * 64;
  int srow = lane >> 3, scolel = (lane & 7) * 8;

  for (int c = 0; c < 8; ++c) {
    #pragma unroll
    for (int i = 0; i < 2; ++i) {
      int w2i = (wid << 1) + i;              // 0..7, wave-uniform
      size_t g = rowbase + (size_t)(c * 64 + w2i * 8 + srow) * 1024 + scolel;
      load_lds16(kbuf + g, (char*)lds + w2i * 1024);
      load_lds16(vbuf + g, (char*)lds + 8192 + w2i * 1024);
    }
    __syncthreads();
    const ushort* Ks = lds;
    const ushort* Vs = lds + 4096;
    #pragma unroll
    for (int t = 0; t < 16; ++t) {
      int nn = (wid << 4) + t;
      s16x8 k8 = *(const s16x8*)(Ks + nn * 64 + d0);
      s16x8 v8 = *(const s16x8*)(Vs + nn * 64 + e0);
      float kf[8], vf[8];
      #pragma unroll
      for (int i = 0; i < 8; ++i) { kf[i] = bf2f((ushort)k8[i]); vf[i] = bf2f((ushort)v8[i]); }
      #pragma unroll
      for (int i = 0; i < 8; ++i) {
        sk[i] += kf[i];
        #pragma unroll
        for (int j = 0; j < 8; ++j) acc[i][j] += kf[i] * vf[j];
      }
    }
    __syncthreads();
  }
  float* red = (float*)lds;
  for (int w = 0; w < 4; ++w) {
    if (wid == w) {
      #pragma unroll
      for (int i = 0; i < 8; ++i)
        #pragma unroll
        for (int j = 0; j < 8; ++j) {
          int idx = (d0 + i) * 64 + e0 + j;
          if (w == 0) red[idx] = acc[i][j];
          else        red[idx] += acc[i][j];
        }
    }
    __syncthreads();
  }
  float* kvo = kvg + bh * 4096;
  #pragma unroll
  for (int i = 0; i < 16; ++i) {
    int idx = tid + i * 256;
    atomicAdd(&kvo[idx], red[idx]);
  }
  if ((lane & 7) == 0) {
    #pragma unroll
    for (int i = 0; i < 8; ++i) atomicAdd(&sumkg[bh * 64 + d0 + i], sk[i]);
  }
}

// ---------------- stage 3: y = (q @ kv) / (q . sumk), bf16 out ----------------
__global__ __launch_bounds__(256, 2) void k_num(
    const ushort* __restrict__ qbuf, const float* __restrict__ kvg,
    const float* __restrict__ sumkg, ushort* __restrict__ ybuf)
{
  __shared__ float kvs[4096];
  __shared__ float sks[64];
  int bh = blockIdx.x >> 5, ch = blockIdx.x & 31;
  int b = bh >> 4, h = bh & 15;
  int tid = threadIdx.x;
  #pragma unroll
  for (int i = 0; i < 16; ++i) kvs[tid + i * 256] = kvg[bh * 4096 + tid + i * 256];
  if (tid < 64) sks[tid] = sumkg[bh * 64 + tid];
  __syncthreads();

  int rl = tid >> 2, eq = (tid & 3) << 4;
  size_t row0 = (size_t)b * 4096 + ch * 128 + rl;
  const ushort* q0 = qbuf + row0 * 1024 + h * 64;
  const ushort* q1 = q0 + (size_t)64 * 1024;
  s16x8 qa[8], qb[8];
  #pragma unroll
  for (int i = 0; i < 8; ++i) { qa[i] = *(const s16x8*)(q0 + i * 8); qb[i] = *(const s16x8*)(q1 + i * 8); }

  float a0[16] = {}, a1[16] = {};
  float den0 = 0.f, den1 = 0.f;
  #pragma unroll
  for (int d = 0; d < 64; ++d) {
    float x0 = bf2f((ushort)qa[d >> 3][d & 7]);
    float x1 = bf2f((ushort)qb[d >> 3][d & 7]);
    float s = sks[d];
    den0 += x0 * s; den1 += x1 * s;
    const f32x4* kr = (const f32x4*)&kvs[d * 64 + eq];
    #pragma unroll
    for (int j = 0; j < 4; ++j) {
      f32x4 k4 = kr[j];
      #pragma unroll
      for (int u = 0; u < 4; ++u) {
        a0[j * 4 + u] += x0 * k4[u];
        a1[j * 4 + u] += x1 * k4[u];
      }
    }
  }
  float i0 = 1.f / den0, i1 = 1.f / den1;
  ushort* y0 = ybuf + row0 * 1024 + h * 64 + eq;
  ushort* y1 = y0 + (size_t)64 * 1024;
  s16x8 p0[2], p1[2];
  #pragma unroll
  for (int j = 0; j < 16; ++j) {
    p0[j >> 3][j & 7] = (short)f2bf(a0[j] * i0);
    p1[j >> 3][j & 7] = (short)f2bf(a1[j] * i1);
  }
  *(s16x8*)y0 = p0[0]; *((s16x8*)y0 + 1) = p0[1];
  *(s16x8*)y1 = p1[0]; *((s16x8*)y1 + 1) = p1[1];
}

extern "C" void kernel_launch(void* const* d_in, const int* in_sizes, int n_in,
                              void* d_out, int out_size, void* d_ws, size_t ws_size,
                              hipStream_t stream)
{
  const float* x  = (const float*)d_in[0];
  const float* Wq = (const float*)d_in[1];
  const float* bq = (const float*)d_in[2];
  const float* Wk = (const float*)d_in[3];
  const float* bk = (const float*)d_in[4];
  const float* Wv = (const float*)d_in[5];
  const float* bv = (const float*)d_in[6];
  const float* Wp = (const float*)d_in[7];
  const float* bp = (const float*)d_in[8];

  char* ws = (char*)d_ws;
  ushort* xb    = (ushort*)(ws + 0);          // 33,554,432 B  x in bf16
  ushort* qkvT  = (ushort*)(ws + 33554432);   //  6,291,456 B  [Wq|Wk|Wv]^T bf16
  ushort* wpT   = (ushort*)(ws + 39845888);   //  2,097,152 B  Wp^T bf16
  ushort* ybuf  = (ushort*)(ws + 41943040);   // 33,554,432 B  k (then aliased as y)
  float*  kvg   = (float*)(ws + 75497472);    //  1,048,576 B  kv fp32
  float*  sumkg = (float*)(ws + 76546048);    //     16,384 B  sum_k fp32

  // v and q live in d_out (67,108,864 B of scratch, dead before final GEMM)
  ushort* vbuf = (ushort*)d_out;
  ushort* qbuf = (ushort*)d_out + 16777216;
  ushort* kbuf = ybuf;

  hipMemsetAsync(kvg, 0, 1064960, stream);                       // kv + sumk
  k_cvt_x<<<8192, 256, 0, stream>>>(x, xb, 2097152);
  k_transposeW<<<dim3(32, 32, 4), dim3(32, 8), 0, stream>>>(Wq, Wk, Wv, Wp, qkvT, wpT);
  k_gemm<0><<<768, 512, 0, stream>>>(xb, qkvT, bq, bk, bv, qbuf, kbuf, vbuf, nullptr, 3072);
  k_kv<<<512, 256, 0, stream>>>(kbuf, vbuf, kvg, sumkg);
  k_num<<<2048, 256, 0, stream>>>(qbuf, kvg, sumkg, ybuf);
  k_gemm<1><<<256, 512, 0, stream>>>(ybuf, wpT, bp, nullptr, nullptr,
                                     nullptr, nullptr, nullptr, (float*)d_out, 1024);
}

// Round 5
// 292.485 us; speedup vs baseline: 1.0519x; 1.0519x over previous
//
#include <hip/hip_runtime.h>
#include <hip/hip_bf16.h>

typedef __attribute__((ext_vector_type(4))) float f32x4;
typedef __attribute__((ext_vector_type(4))) short s16x4;
typedef __attribute__((ext_vector_type(8))) short s16x8;
typedef __attribute__((ext_vector_type(8))) __bf16 bf16x8;

#define DEV static __device__ __forceinline__

DEV float bf2f(ushort u){
  unsigned x = ((unsigned)u) << 16;
  return __builtin_bit_cast(float, x);
}
DEV ushort f2bf(float f){
  unsigned x = __builtin_bit_cast(unsigned, f);
  x += 0x7fffu + ((x >> 16) & 1u);
  return (ushort)(x >> 16);
}
DEV void load_lds16(const void* g, void* l){
  __builtin_amdgcn_global_load_lds((const __attribute__((address_space(1))) void*)g,
                                   (__attribute__((address_space(3))) void*)l, 16, 0, 0);
}

// ---------------- stage 0a: x fp32 -> bf16 ----------------
__global__ __launch_bounds__(256) void k_cvt_x(const float* __restrict__ x,
                                               ushort* __restrict__ xb, int n8){
  int i = blockIdx.x * 256 + threadIdx.x;
  if (i >= n8) return;
  const f32x4* p = (const f32x4*)(x + (size_t)i * 8);
  f32x4 a = p[0], b = p[1];
  s16x8 o;
  o[0]=(short)f2bf(a[0]); o[1]=(short)f2bf(a[1]); o[2]=(short)f2bf(a[2]); o[3]=(short)f2bf(a[3]);
  o[4]=(short)f2bf(b[0]); o[5]=(short)f2bf(b[1]); o[6]=(short)f2bf(b[2]); o[7]=(short)f2bf(b[3]);
  *(s16x8*)(xb + (size_t)i * 8) = o;
}

// ---------------- stage 0b: W [K][N] fp32 -> Wt [N][K] bf16 ----------------
__global__ void k_transposeW(const float* __restrict__ Wq, const float* __restrict__ Wk,
                             const float* __restrict__ Wv, const float* __restrict__ Wp,
                             ushort* __restrict__ qkvT, ushort* __restrict__ wpT){
  __shared__ float tile[32][33];
  int z = blockIdx.z;
  const float* W = (z == 0) ? Wq : (z == 1) ? Wk : (z == 2) ? Wv : Wp;
  ushort* out = (z < 3) ? (qkvT + (size_t)z * 1024 * 1024) : wpT;
  int bx = blockIdx.x * 32, by = blockIdx.y * 32;
  int tx = threadIdx.x, ty = threadIdx.y;
  #pragma unroll
  for (int j = 0; j < 32; j += 8)
    tile[ty + j][tx] = W[(size_t)(by + ty + j) * 1024 + bx + tx];
  __syncthreads();
  #pragma unroll
  for (int j = 0; j < 32; j += 8)
    out[(size_t)(bx + ty + j) * 1024 + by + tx] = f2bf(tile[tx][ty + j]);
}

// ---------------- MFMA GEMM, 256x256, BK=64, 4-phase + FRAG READ-AHEAD -----
// C[M][N] = A[M][K] * Bt[N][K]^T, K=1024. 512 threads = 8 waves (2Mx4N),
// per-wave 128x64. Phases: p1(mh0,kk0) p2(mh1,kk0) p3(mh1,kk1) p4(mh0,kk1).
// KEY (R5): fragment double-buffering — each phase issues the ds_reads for
// phase p+1 (sets alternate aX/aY, bX/bY), then MFMAs phase p. LDS delivery
// overlaps MFMA via compiler-counted lgkmcnt. One barrier per phase.
// Staging slots (2 DMA rounds/phase, all >=2-phase lead):
//   p1: B2B3(t+1)->nxt  p2: A0A2(t+1)->nxt  p3: A1A3(t+1)->nxt
//   p4: B0B1(t+2)->cur  (B region of cur is dead after p2's bY read)
// vmcnt(2) at p1-start (drains A1A3(t)) and p4-start (drains B+A0A2(t+1)).
// FIFO sim verified: queue at p1-entry = [A1A3(t), B0B1(t+1)].
// Swizzle: 16B-granule ^= row&7 (A) / (row>>2)&7 (B); frag reads at granule
// hi^(L&7): uniform over banks, conflict-free. B-frag N-permutation: slot L
// holds B-row wc*64+L*4+n -> lane's 4 n-acc are 4 contiguous output cols.
template<int MODE>
__global__ __launch_bounds__(512, 1) void k_gemm(
    const ushort* __restrict__ A, const ushort* __restrict__ Bt,
    const float* __restrict__ b0, const float* __restrict__ b1, const float* __restrict__ b2,
    ushort* __restrict__ oQ, ushort* __restrict__ oK, ushort* __restrict__ oV,
    float* __restrict__ oF, int N)
{
  const int K = 1024;
  const int NT = 16;                        // K / 64
  __shared__ ushort ldsA[2][16384];         // 2 x 32KB: [256 rows][64 cols bf16]
  __shared__ ushort ldsB[2][16384];

  int wg = blockIdx.x;
  int cpx = gridDim.x >> 3;                 // grids are multiples of 8
  wg = (wg & 7) * cpx + (wg >> 3);          // XCD-aware swizzle (bijective)
  int nbn = N >> 8;
  int bmi = wg / nbn, bni = wg - bmi * nbn;
  int m0 = bmi << 8, n0 = bni << 8;
  int tid = threadIdx.x, wid = tid >> 6, lane = tid & 63;
  int wr = wid >> 2, wc = wid & 3;
  int hi = lane >> 4, L = lane & 15;

  // ---- staging sources (linear LDS dest, inverse-swizzled global source)
  int rr = tid >> 3;                                   // row within 8KB round
  int gaA = ((tid & 7) ^ (rr & 7)) << 3;               // A src col (elements)
  int gaB = ((tid & 7) ^ ((tid >> 5) & 7)) << 3;       // B src col (elements)
  const ushort* gA = A  + (size_t)(m0 + rr) * K + gaA;
  const ushort* gB = Bt + (size_t)(n0 + rr) * K + gaB;
  int ldst = wid << 10;                                // + round*8192

  // ---- fragment read addresses
  int swz = (hi ^ (L & 7)) << 4;            // ^ 64 for kk=1
  int arow = (wr * 128 + L) << 7;           // + mh*8192 + m*2048
  int brow = ((wc * 64 + L * 4)) << 7;      // + n*128

  f32x4 acc[8][4] = {};
  bf16x8 aX[4], aY[4], bX[4], bY[4];

  #define RD_A(SET, BASE, MH, KX)                                              \
    _Pragma("unroll")                                                          \
    for (int m = 0; m < 4; ++m)                                                \
      SET[m] = *(const bf16x8*)((BASE) + arow + (MH) * 8192 + (m << 11) + (swz ^ (KX)));
  #define RD_B(SET, BASE, KX)                                                  \
    _Pragma("unroll")                                                          \
    for (int n = 0; n < 4; ++n)                                                \
      SET[n] = *(const bf16x8*)((BASE) + brow + (n << 7) + (swz ^ (KX)));
  #define MF(MOFF, ASET, BSET)                                                 \
    __builtin_amdgcn_s_setprio(1);                                             \
    _Pragma("unroll")                                                          \
    for (int m = 0; m < 4; ++m)                                                \
      _Pragma("unroll")                                                        \
      for (int n = 0; n < 4; ++n)                                              \
        acc[m + (MOFF)][n] =                                                   \
          __builtin_amdgcn_mfma_f32_16x16x32_bf16(ASET[m], BSET[n], acc[m + (MOFF)][n], 0, 0, 0); \
    __builtin_amdgcn_s_setprio(0);

  // staging rounds (16B per thread each)
  #define ST_B0(SB, kof) load_lds16(gB + (kof),                   (SB) + ldst);
  #define ST_B1(SB, kof) load_lds16(gB + (size_t) 64 * K + (kof), (SB) + 8192  + ldst);
  #define ST_B2(SB, kof) load_lds16(gB + (size_t)128 * K + (kof), (SB) + 16384 + ldst);
  #define ST_B3(SB, kof) load_lds16(gB + (size_t)192 * K + (kof), (SB) + 24576 + ldst);
  #define ST_A0(SA, kof) load_lds16(gA + (kof),                   (SA) + ldst);
  #define ST_A2(SA, kof) load_lds16(gA + (size_t)128 * K + (kof), (SA) + 16384 + ldst);
  #define ST_A1(SA, kof) load_lds16(gA + (size_t) 64 * K + (kof), (SA) + 8192  + ldst);
  #define ST_A3(SA, kof) load_lds16(gA + (size_t)192 * K + (kof), (SA) + 24576 + ldst);

  // ---- prologue: stage tile 0 -> buf0 (order B0..B3, A0, A2, A1, A3),
  //      then B0B1(t1) -> buf1.  vmcnt(4) drains t0's B + A0 + A2.
  {
    char* SA0 = (char*)&ldsA[0][0];
    char* SB0 = (char*)&ldsB[0][0];
    char* SB1 = (char*)&ldsB[1][0];
    ST_B0(SB0, 0) ST_B1(SB0, 0) ST_B2(SB0, 0) ST_B3(SB0, 0)
    ST_A0(SA0, 0) ST_A2(SA0, 0) ST_A1(SA0, 0) ST_A3(SA0, 0)
    ST_B0(SB1, 64) ST_B1(SB1, 64)
  }
  asm volatile("s_waitcnt vmcnt(4)" ::: "memory");
  __builtin_amdgcn_s_barrier();
  RD_A(aX, (const char*)&ldsA[0][0], 0, 0)    // frags for p1(t0)
  RD_B(bX, (const char*)&ldsB[0][0], 0)

  int buf = 0;
  for (int t = 0; t < NT; ++t) {
    const char* LA = (const char*)&ldsA[buf][0];
    const char* LB = (const char*)&ldsB[buf][0];
    char* SAn = (char*)&ldsA[buf ^ 1][0];
    char* SBn = (char*)&ldsB[buf ^ 1][0];
    char* SBc = (char*)&ldsB[buf][0];         // p4 stages t+2 into CURRENT B
    size_t k1 = (size_t)(t + 1) << 6;
    size_t k2 = (size_t)(t + 2) << 6;
    bool st1 = (t + 1) < NT, st2 = (t + 2) < NT;

    // ===== p1: MFMA(mh0,kk0) with aX,bX; read aY<-frags(p2) =====
    if (st1) asm volatile("s_waitcnt vmcnt(2)" ::: "memory");  // A1A3(t) landed
    else     asm volatile("s_waitcnt vmcnt(0)" ::: "memory");
    __builtin_amdgcn_s_barrier();
    RD_A(aY, LA, 1, 0)
    if (st1) { ST_B2(SBn, k1) ST_B3(SBn, k1) }
    __builtin_amdgcn_sched_barrier(0);
    MF(0, aX, bX)

    // ===== p2: MFMA(mh1,kk0) with aY,bX; read aX,bY<-frags(p3) =====
    __builtin_amdgcn_s_barrier();
    RD_A(aX, LA, 1, 64)
    RD_B(bY, LB, 64)
    if (st1) { ST_A0(SAn, k1) ST_A2(SAn, k1) }
    __builtin_amdgcn_sched_barrier(0);
    MF(4, aY, bX)

    // ===== p3: MFMA(mh1,kk1) with aX,bY; read aY<-frags(p4) =====
    __builtin_amdgcn_s_barrier();
    RD_A(aY, LA, 0, 64)
    if (st1) { ST_A1(SAn, k1) ST_A3(SAn, k1) }
    __builtin_amdgcn_sched_barrier(0);
    MF(4, aX, bY)

    // ===== p4: MFMA(mh0,kk1) with aY,bY; read aX,bX<-frags(p1,t+1) =====
    asm volatile("s_waitcnt vmcnt(2)" ::: "memory");  // B+A0A2(t+1) landed
    __builtin_amdgcn_s_barrier();
    if (st1) { RD_A(aX, SAn, 0, 0) RD_B(bX, SBn, 0) }
    if (st2) { ST_B0(SBc, k2) ST_B1(SBc, k2) }
    __builtin_amdgcn_sched_barrier(0);
    MF(0, aY, bY)

    buf ^= 1;
  }
  #undef RD_A
  #undef RD_B
  #undef MF

  // ---- epilogue: lane holds 4 contiguous cols (cb4..cb4+3) per row
  int row0 = m0 + wr * 128 + (hi << 2);
  int cb4 = n0 + wc * 64 + (L << 2);
  if constexpr (MODE == 0) {
    f32x4 bias; ushort* dst; bool act;
    if (cb4 < 1024)      { bias = *(const f32x4*)(b0 + cb4);          dst = oQ + cb4;          act = true;  }
    else if (cb4 < 2048) { bias = *(const f32x4*)(b1 + (cb4 - 1024)); dst = oK + (cb4 - 1024); act = true;  }
    else                 { bias = *(const f32x4*)(b2 + (cb4 - 2048)); dst = oV + (cb4 - 2048); act = false; }
    #pragma unroll
    for (int m = 0; m < 8; ++m)
      #pragma unroll
      for (int j = 0; j < 4; ++j) {
        int r = row0 + m * 16 + j;
        s16x4 w;
        #pragma unroll
        for (int n = 0; n < 4; ++n) {
          float v = acc[m][n][j] + bias[n];
          if (act) v = (v > 0.f) ? (v + 1.f) : __expf(v);   // elu(v)+1
          w[n] = (short)f2bf(v);
        }
        *(s16x4*)(dst + (size_t)r * 1024) = w;
      }
  } else {
    f32x4 bias = *(const f32x4*)(b0 + cb4);
    #pragma unroll
    for (int m = 0; m < 8; ++m)
      #pragma unroll
      for (int j = 0; j < 4; ++j) {
        int r = row0 + m * 16 + j;
        f32x4 w;
        #pragma unroll
        for (int n = 0; n < 4; ++n) w[n] = acc[m][n][j] + bias[n];
        *(f32x4*)(oF + (size_t)r * 1024 + cb4) = w;
      }
  }
}

// ---------------- stage 2: kv[bh][64][64] = k^T v ; sumk[bh][64] ----------------
__global__ __launch_bounds__(256, 2) void k_kv(
    const ushort* __restrict__ kbuf, const ushort* __restrict__ vbuf,
    float* __restrict__ kvg, float* __restrict__ sumkg)
{
  __shared__ ushort lds[8192];               // Ks 8KB | Vs 8KB ; reused as fp32 red
  int bh = blockIdx.x >> 3, chunk = blockIdx.x & 7;
  int b = bh >> 4, h = bh & 15;
  int tid = threadIdx.x, wid = tid >> 6, lane = tid & 63;
  int d0 = (lane >> 3) << 3, e0 = (lane & 7) << 3;
  float acc[8][8] = {};
  float sk[8] = {};
  size_t rowbase = ((size_t)b * 4096 + chunk * 512) * 1024 + h * 64;
  int srow = lane >> 3, scolel = (lane & 7) * 8;

  for (int c = 0; c < 8; ++c) {
    #pragma unroll
    for (int i = 0; i < 2; ++i) {
      int w2i = (wid << 1) + i;              // 0..7, wave-uniform
      size_t g = rowbase + (size_t)(c * 64 + w2i * 8 + srow) * 1024 + scolel;
      load_lds16(kbuf + g, (char*)lds + w2i * 1024);
      load_lds16(vbuf + g, (char*)lds + 8192 + w2i * 1024);
    }
    __syncthreads();
    const ushort* Ks = lds;
    const ushort* Vs = lds + 4096;
    #pragma unroll
    for (int t = 0; t < 16; ++t) {
      int nn = (wid << 4) + t;
      s16x8 k8 = *(const s16x8*)(Ks + nn * 64 + d0);
      s16x8 v8 = *(const s16x8*)(Vs + nn * 64 + e0);
      float kf[8], vf[8];
      #pragma unroll
      for (int i = 0; i < 8; ++i) { kf[i] = bf2f((ushort)k8[i]); vf[i] = bf2f((ushort)v8[i]); }
      #pragma unroll
      for (int i = 0; i < 8; ++i) {
        sk[i] += kf[i];
        #pragma unroll
        for (int j = 0; j < 8; ++j) acc[i][j] += kf[i] * vf[j];
      }
    }
    __syncthreads();
  }
  float* red = (float*)lds;
  for (int w = 0; w < 4; ++w) {
    if (wid == w) {
      #pragma unroll
      for (int i = 0; i < 8; ++i)
        #pragma unroll
        for (int j = 0; j < 8; ++j) {
          int idx = (d0 + i) * 64 + e0 + j;
          if (w == 0) red[idx] = acc[i][j];
          else        red[idx] += acc[i][j];
        }
    }
    __syncthreads();
  }
  float* kvo = kvg + bh * 4096;
  #pragma unroll
  for (int i = 0; i < 16; ++i) {
    int idx = tid + i * 256;
    atomicAdd(&kvo[idx], red[idx]);
  }
  if ((lane & 7) == 0) {
    #pragma unroll
    for (int i = 0; i < 8; ++i) atomicAdd(&sumkg[bh * 64 + d0 + i], sk[i]);
  }
}

// ---------------- stage 3: y = (q @ kv) / (q . sumk), bf16 out ----------------
__global__ __launch_bounds__(256, 2) void k_num(
    const ushort* __restrict__ qbuf, const float* __restrict__ kvg,
    const float* __restrict__ sumkg, ushort* __restrict__ ybuf)
{
  __shared__ float kvs[4096];
  __shared__ float sks[64];
  int bh = blockIdx.x >> 5, ch = blockIdx.x & 31;
  int b = bh >> 4, h = bh & 15;
  int tid = threadIdx.x;
  #pragma unroll
  for (int i = 0; i < 16; ++i) kvs[tid + i * 256] = kvg[bh * 4096 + tid + i * 256];
  if (tid < 64) sks[tid] = sumkg[bh * 64 + tid];
  __syncthreads();

  int rl = tid >> 2, eq = (tid & 3) << 4;
  size_t row0 = (size_t)b * 4096 + ch * 128 + rl;
  const ushort* q0 = qbuf + row0 * 1024 + h * 64;
  const ushort* q1 = q0 + (size_t)64 * 1024;
  s16x8 qa[8], qb[8];
  #pragma unroll
  for (int i = 0; i < 8; ++i) { qa[i] = *(const s16x8*)(q0 + i * 8); qb[i] = *(const s16x8*)(q1 + i * 8); }

  float a0[16] = {}, a1[16] = {};
  float den0 = 0.f, den1 = 0.f;
  #pragma unroll
  for (int d = 0; d < 64; ++d) {
    float x0 = bf2f((ushort)qa[d >> 3][d & 7]);
    float x1 = bf2f((ushort)qb[d >> 3][d & 7]);
    float s = sks[d];
    den0 += x0 * s; den1 += x1 * s;
    const f32x4* kr = (const f32x4*)&kvs[d * 64 + eq];
    #pragma unroll
    for (int j = 0; j < 4; ++j) {
      f32x4 k4 = kr[j];
      #pragma unroll
      for (int u = 0; u < 4; ++u) {
        a0[j * 4 + u] += x0 * k4[u];
        a1[j * 4 + u] += x1 * k4[u];
      }
    }
  }
  float i0 = 1.f / den0, i1 = 1.f / den1;
  ushort* y0 = ybuf + row0 * 1024 + h * 64 + eq;
  ushort* y1 = y0 + (size_t)64 * 1024;
  s16x8 p0[2], p1[2];
  #pragma unroll
  for (int j = 0; j < 16; ++j) {
    p0[j >> 3][j & 7] = (short)f2bf(a0[j] * i0);
    p1[j >> 3][j & 7] = (short)f2bf(a1[j] * i1);
  }
  *(s16x8*)y0 = p0[0]; *((s16x8*)y0 + 1) = p0[1];
  *(s16x8*)y1 = p1[0]; *((s16x8*)y1 + 1) = p1[1];
}

extern "C" void kernel_launch(void* const* d_in, const int* in_sizes, int n_in,
                              void* d_out, int out_size, void* d_ws, size_t ws_size,
                              hipStream_t stream)
{
  const float* x  = (const float*)d_in[0];
  const float* Wq = (const float*)d_in[1];
  const float* bq = (const float*)d_in[2];
  const float* Wk = (const float*)d_in[3];
  const float* bk = (const float*)d_in[4];
  const float* Wv = (const float*)d_in[5];
  const float* bv = (const float*)d_in[6];
  const float* Wp = (const float*)d_in[7];
  const float* bp = (const float*)d_in[8];

  char* ws = (char*)d_ws;
  ushort* xb    = (ushort*)(ws + 0);          // 33,554,432 B  x in bf16
  ushort* qkvT  = (ushort*)(ws + 33554432);   //  6,291,456 B  [Wq|Wk|Wv]^T bf16
  ushort* wpT   = (ushort*)(ws + 39845888);   //  2,097,152 B  Wp^T bf16
  ushort* ybuf  = (ushort*)(ws + 41943040);   // 33,554,432 B  k (then aliased as y)
  float*  kvg   = (float*)(ws + 75497472);    //  1,048,576 B  kv fp32
  float*  sumkg = (float*)(ws + 76546048);    //     16,384 B  sum_k fp32

  // v and q live in d_out (67,108,864 B of scratch, dead before final GEMM)
  ushort* vbuf = (ushort*)d_out;
  ushort* qbuf = (ushort*)d_out + 16777216;
  ushort* kbuf = ybuf;

  hipMemsetAsync(kvg, 0, 1064960, stream);                       // kv + sumk
  k_cvt_x<<<8192, 256, 0, stream>>>(x, xb, 2097152);
  k_transposeW<<<dim3(32, 32, 4), dim3(32, 8), 0, stream>>>(Wq, Wk, Wv, Wp, qkvT, wpT);
  k_gemm<0><<<768, 512, 0, stream>>>(xb, qkvT, bq, bk, bv, qbuf, kbuf, vbuf, nullptr, 3072);
  k_kv<<<512, 256, 0, stream>>>(kbuf, vbuf, kvg, sumkg);
  k_num<<<2048, 256, 0, stream>>>(qbuf, kvg, sumkg, ybuf);
  k_gemm<1><<<256, 512, 0, stream>>>(ybuf, wpT, bp, nullptr, nullptr,
                                     nullptr, nullptr, nullptr, (float*)d_out, 1024);
}